// Round 9
// baseline (7404.121 us; speedup 1.0000x reference)
//
#include <hip/hip_runtime.h>

// LSTMPredictor: B=32,T=512,H=128,L=5,IN=1,OUT=16,future=18 -> one 514-step scan.
// R20 = R19 (best verified: 890us) + chunk-8 publish amortization:
//   - chunk publish (t&7)==0 (was (t&3)==0): consumer flag-poll spin entry (one
//     dependent ~250-300cyc agent-scope L2 round trip) now every 8 steps instead of
//     4 (~70 -> ~35 cyc/step), and the top-of-step pub drain+barrier rate halves.
//   - backpressure threshold t-16 (was t-15). Proof: producer at step t overwrites
//     slot (t-1)&15 holding h(t-17); consumer consumed h(t-17) during its step t-18,
//     attested by flag >= t-17; t-16 keeps one step margin and absorbs chunk-8 flag
//     staleness. Deadlock-free (consumer progress raises flag).
// Closed case (R14/R17/R19 triangulation): SQ_LDS_BANK_CONFLICT = 4.0 cyc per af
// ds_read_b128 exactly, invariant under layout -> structural cost of wave64 b128
// reads, not fixable. R19's write-depermute (rho(m), stride 272) kept: worth ~8us.
// Eliminated suspects (measured): LDS read throughput (R13/R17), same-step L2 loads
// (R17 +72%), publish drain + af latency (R18 neutral), per-step flag prefetch
// (R15 -13%, vmcnt FIFO coupling), dependent MFMA gate-chains (R14 -7%).
// R13 (kept): both weight halves in 128 VGPRs. R12 (kept): scale-folded weights/bias,
// bias in MFMA C-init, v_exp/v_rcp activations (R16 rcp-pairing was +14us, reverted).
// 10 WGs = 5 layers x 2 batch-halves, 512 thr, 1 WG/CU.

typedef _Float16 v8h __attribute__((ext_vector_type(8)));
typedef _Float16 h4v __attribute__((ext_vector_type(4)));
typedef float f4 __attribute__((ext_vector_type(4)));

#define RING 16
#define TAIL 500
#define GUARD (1<<16)
#define ASTR 272                      // A2 row stride in f16 (136 dwords = 8 mod 32)

#define FLAGL_OFF   0                 // int flagL[2*5][64]
#define FCFLAG_OFF  (64*1024)        // int fcflag[2][64]
#define FCOUT_OFF   (128*1024)       // float fcout[2][2][16]
#define RING_OFF    (256*1024)       // f16 ring[8][16][16][128] = 512KB
#define WCATR_OFF   (2*1024*1024)    // f16 WcatR[5][512][128] (hh, scale-folded) = 640KB
#define WL_OFF      (3*1024*1024)    // f16 WLg[5][16][512][8] (ih, ktq-major, scale-folded)
#define BIASC_OFF   (4*1024*1024)    // f32 biasC[5][128][4] (scale-folded)

#define SCL_SIG (-1.4426950408889634f)   // -log2(e)
#define SCL_TNH (-2.8853900817779268f)   // -2*log2(e)

#define AGENT __HIP_MEMORY_SCOPE_AGENT
#define LD(p)    __hip_atomic_load((p),  __ATOMIC_RELAXED, AGENT)
#define ST(p,v)  __hip_atomic_store((p), (v), __ATOMIC_RELAXED, AGENT)
#define LD64(p)  __hip_atomic_load((const unsigned long long*)(p), __ATOMIC_RELAXED, AGENT)
#define ST64(p,v) __hip_atomic_store((unsigned long long*)(p), (v), __ATOMIC_RELAXED, AGENT)

union HU { unsigned long long u; h4v v; };

__device__ __forceinline__ void bar_lgkm() {
    asm volatile("s_waitcnt lgkmcnt(0)\n\ts_barrier" ::: "memory");
}
__device__ __forceinline__ void drain_vm() {
    asm volatile("s_waitcnt vmcnt(0)" ::: "memory");
}
__device__ __forceinline__ float exp2_hw(float x) {      // 2^x, one v_exp_f32
    float r; asm("v_exp_f32 %0, %1" : "=v"(r) : "v"(x)); return r;
}
__device__ __forceinline__ float sigm2(float s) {        // s = -log2e * x  -> sigmoid(x)
    return __builtin_amdgcn_rcpf(1.f + exp2_hw(s));
}
__device__ __forceinline__ float tanh2(float s) {        // s = -2log2e * x -> tanh(x)
    return fmaf(2.f, __builtin_amdgcn_rcpf(1.f + exp2_hw(s)), -1.f);
}

// -------- init: flags=0, WcatR (hh f16), WLg (ih f16 ktq-major), biasC — scale-folded ----
__global__ void lstm_init(const float* __restrict__ WihR, const float* __restrict__ Whh,
                          const float* __restrict__ bih,  const float* __restrict__ bhh,
                          char* __restrict__ ws)
{
    int idx = blockIdx.x * blockDim.x + threadIdx.x;
    int stride = gridDim.x * blockDim.x;
    int* wsi = (int*)ws;
    for (int i = idx; i < 65536; i += stride) wsi[i] = 0;

    _Float16* WR = (_Float16*)(ws + WCATR_OFF);        // [l][n][k<128]
    for (int i = idx; i < 5*512*128; i += stride) {
        int k = i & 127, n = (i >> 7) & 511, l = i >> 16;
        float s = ((n >> 7) == 2) ? SCL_TNH : SCL_SIG;
        WR[i] = (_Float16)(s * Whh[(l*512 + n)*128 + k]);
    }
    _Float16* WLp = (_Float16*)(ws + WL_OFF);          // [l][ktq][n][8]
    for (int i = idx; i < 5*16*512*8; i += stride) {
        int j = i & 7, n = (i >> 3) & 511, ktq = (i >> 12) & 15, l = i >> 16;
        int k = (ktq >> 2)*32 + (ktq & 3)*8 + j;       // ih column (0..127)
        float s = ((n >> 7) == 2) ? SCL_TNH : SCL_SIG;
        WLp[i] = (_Float16)(l > 0 ? s * WihR[((l-1)*512 + n)*128 + k] : 0.f);
    }
    float* BC = (float*)(ws + BIASC_OFF);              // [l][r][g]
    for (int i = idx; i < 5*128*4; i += stride) {
        int g = i & 3, r = (i >> 2) & 127, l = i >> 9;
        float s = (g == 2) ? SCL_TNH : SCL_SIG;
        BC[i] = s * (bih[l*512 + g*128 + r] + bhh[l*512 + g*128 + r]);
    }
}

// -------- main: persistent pipeline --------
__global__ void __launch_bounds__(512)
lstm_main(const float* __restrict__ x_in, const float* __restrict__ Wih0,
          const float* __restrict__ W1,   const float* __restrict__ b1,
          const float* __restrict__ W2,   const float* __restrict__ b2,
          float* __restrict__ out, char* __restrict__ ws)
{
    __shared__ __align__(16) _Float16 A2[2][16][ASTR];  // 17KB: A dbuf, PHYSICAL rows
    __shared__ float  fcb[2304];                        // 9.2KB: FC scratch (zbsT / z2F)
    __shared__ float  xcur[2][16];                      // l0: x[t] dbuf

    const int tid  = threadIdx.x;
    const int lane = tid & 63;
    const int w    = tid >> 6;              // wave 0..7 -> n-tiles {w,8+w,16+w,24+w}
    const int col  = lane & 15, quad = lane >> 4;
    const int r    = w*16 + col;            // this lane's hidden row
    const int rowR = ((col & 3) << 2) | (col >> 2);  // rho(col): physical row for A-reads
    const int p = blockIdx.x / 5, l = blockIdx.x % 5;
    const bool isProd = (l < 4), isCons = (l > 0);
    const int tm = tid >> 5, tr0 = (tid & 31) * 4;   // transport map: (phys row, r0)

    int*   flagL  = (int*)(ws + FLAGL_OFF);
    int*   fcflagP= (int*)(ws + FCFLAG_OFF) + p*64;
    float* fcoutG = (float*)(ws + FCOUT_OFF);
    _Float16* ringH = (_Float16*)(ws + RING_OFF);
    const _Float16* WR  = (const _Float16*)(ws + WCATR_OFF) + l*512*128;
    const _Float16* WLh = (const _Float16*)(ws + WL_OFF) + (size_t)l*65536;

    int* upflag = flagL + (p*5 + (l > 0 ? l-1 : 0))*64;
    int* dnflag = flagL + (p*5 + (l < 4 ? l+1 : 4))*64;
    int* myflag = flagL + (p*5 + l)*64;
    _Float16* upRingH = ringH + (p*4 + (l > 0 ? l-1 : 0))*RING*2048;
    _Float16* myRingH = ringH + (p*4 + (l < 4 ? l   : 0))*RING*2048;

    // ---- hh weights: registers (64 VGPRs) ----
    v8h bf[4][4];
#pragma unroll
    for (int q = 0; q < 4; ++q)
#pragma unroll
        for (int kt = 0; kt < 4; ++kt)
            bf[q][kt] = *(const v8h*)&WR[((q*8 + w)*16 + col)*128 + kt*32 + quad*8];

    // ---- ih weights: registers (64 VGPRs), one-time load ----
    v8h wfr[4][4];                       // [kt-4][q]
    if (isCons) {
#pragma unroll
        for (int kq = 0; kq < 4; ++kq)
#pragma unroll
            for (int q = 0; q < 4; ++q)
                wfr[kq][q] = *(const v8h*)&WLh[(((kq*4 + quad)*512) + (q*8 + w)*16 + col)*8];
    } else {
#pragma unroll
        for (int kq = 0; kq < 4; ++kq)
#pragma unroll
            for (int q = 0; q < 4; ++q)
                wfr[kq][q] = (v8h)(_Float16)0.f;
    }

    // ---- loop-invariant per-lane constants: bias (scale-folded) + l0 input weights ----
    const f4 bvR = ((const f4*)(ws + BIASC_OFF))[l*128 + r];
    f4 wxR = (f4){0.f, 0.f, 0.f, 0.f};
    if (l == 0) {
        wxR.x = SCL_SIG * Wih0[r];
        wxR.y = SCL_SIG * Wih0[128 + r];
        wxR.z = SCL_TNH * Wih0[256 + r];
        wxR.w = SCL_SIG * Wih0[384 + r];
    }

    for (int i = tid; i < 2*16*ASTR; i += 512) ((_Float16*)A2)[i] = (_Float16)0.f;
    if (l == 0 && tid < 16) xcur[0][tid] = x_in[(p*16 + tid)*512];

    int lastup = 0, lastdn = 0, lastfc = 0;
    if (isCons) {                       // seed up-h(0) (physical rows end-to-end)
        int g = 0;
        while (lastup < 1) { if (++g > GUARD) break; lastup = LD(upflag); }
        HU u; u.u = LD64(&upRingH[(0*16 + tm)*128 + tr0]);
        *(h4v*)&A2[0][tm][128 + tr0] = u.v;
    }
    __syncthreads();

    float c[4] = {0.f, 0.f, 0.f, 0.f};

    for (int t = 0; t < 514; ++t) {
        const int cur = t & 1, nxt = (t + 1) & 1;

        // ---- steady ring store of h(t-1) + chunk-8 publish (physical rows) ----
        if (isProd && t > 0 && t <= TAIL) {
            HU u; u.v = *(const h4v*)&A2[cur][tm][tr0];
            ST64(&myRingH[(((t-1) & 15)*16 + tm)*128 + tr0], u.u);
        }
        if (t > 0 && t <= TAIL && (t & 7) == 0) {
            drain_vm();
            bar_lgkm();
            if (tid == 0) ST(myflag, t);
        }

        // ---- steady prefetch up-h(t+1) ----
        unsigned long long rv = 0;
        if (isCons && t + 1 < TAIL) {
            if (lastup < t + 2) {
                int g = 0;
                while (lastup < t + 2) { if (++g > GUARD) break; lastup = LD(upflag); }
            }
            rv = LD64(&upRingH[(((t+1) & 15)*16 + tm)*128 + tr0]);
        }
        // ---- tail current-fetch up-h(t) ----
        if (isCons && t >= TAIL) {
            if (lastup < t + 1) {
                int g = 0;
                while (lastup < t + 1) { if (++g > GUARD) break; lastup = LD(upflag); }
            }
            HU u; u.u = LD64(&upRingH[((t & 15)*16 + tm)*128 + tr0]);
            *(h4v*)&A2[cur][tm][128 + tr0] = u.v;
        }
        if (isCons && t >= TAIL) bar_lgkm();

        // ---- l0 x prefetch (steady) ----
        if (l == 0 && t + 1 < 512 && tid < 16)
            xcur[nxt][tid] = x_in[(p*16 + tid)*512 + (t+1)];
        // ---- backpressure (rare); slot (t-1)&15 overwrite needs flag >= t-17;
        //      t-16 keeps one step margin + absorbs chunk-8 staleness ----
        if (isProd && t >= RING && lastdn < t - 16) {
            int g = 0;
            while (lastdn < t - 16) { if (++g > GUARD) break; lastdn = LD(dnflag); }
        }

        // ================= MFMA: gates = A @ [Whh | Wih]^T (bias in C-init) ==========
        // kt-outer / q-inner: 4 independent accumulators, dep-distance 4 -> pipelined.
        // A-read at physical row rho(col): uniform 8 dwords/bank.
        const _Float16* Ac = &A2[cur][0][0] + rowR*ASTR + quad*8;
        f4 acc[4];
        acc[0] = (f4){bvR.x, bvR.x, bvR.x, bvR.x};
        acc[1] = (f4){bvR.y, bvR.y, bvR.y, bvR.y};
        acc[2] = (f4){bvR.z, bvR.z, bvR.z, bvR.z};
        acc[3] = (f4){bvR.w, bvR.w, bvR.w, bvR.w};
#pragma unroll
        for (int kt = 0; kt < 4; ++kt) {                 // hh: B from registers
            v8h af = *(const v8h*)(Ac + kt*32);
#pragma unroll
            for (int q = 0; q < 4; ++q)
                acc[q] = __builtin_amdgcn_mfma_f32_16x16x32_f16(af, bf[q][kt], acc[q], 0, 0, 0);
        }
        if (isCons) {
#pragma unroll
            for (int kt = 4; kt < 8; ++kt) {             // ih: B from registers
                v8h af = *(const v8h*)(Ac + 128 + (kt-4)*32);
#pragma unroll
                for (int q = 0; q < 4; ++q)
                    acc[q] = __builtin_amdgcn_mfma_f32_16x16x32_f16(af, wfr[kt-4][q], acc[q], 0, 0, 0);
            }
        }

        // ---- l0 tail: feedback x into xcur[cur] ----
        if (l == 0 && t >= 512) {
            if (tid < 16) {
                int need = t - 511, g = 0;
                while (lastfc < need) { if (++g > GUARD) break; lastfc = LD(fcflagP); }
                xcur[cur][tid] = LD(&fcoutG[(p*2 + (t - 512))*16 + tid]);
            }
            bar_lgkm();
        }

        // ================= cell update: IN-REGISTER (lane owns 4 cells) ==========
        float xts[4];
        if (l == 0) {
#pragma unroll
            for (int i = 0; i < 4; ++i) xts[i] = xcur[cur][quad*4 + i];
        }
        float hv[4];
#pragma unroll
        for (int i = 0; i < 4; ++i) {
            float gi = acc[0][i], gf = acc[1][i];
            float gG = acc[2][i], gO = acc[3][i];
            if (l == 0) {
                gi = fmaf(wxR.x, xts[i], gi); gf = fmaf(wxR.y, xts[i], gf);
                gG = fmaf(wxR.z, xts[i], gG); gO = fmaf(wxR.w, xts[i], gO);
            }
            float si = sigm2(gi), sf = sigm2(gf), gt = tanh2(gG), so = sigm2(gO);
            c[i] = fmaf(sf, c[i], si * gt);
            hv[i] = so * tanh2(c[i] * SCL_TNH);
            // physical row rho(m) = i*4+quad: bank octets {0,8,16,24} disjoint.
            A2[nxt][i*4 + quad][r] = (_Float16)hv[i];    // own-h(t) for step t+1
        }
        if (isCons && t + 1 < TAIL) {                    // prefetched up-h(t+1)
            HU u; u.u = rv;
            *(h4v*)&A2[nxt][tm][128 + tr0] = u.v;
        }
        bar_lgkm();

        // ---- tail: store h(t) + per-step publish ----
        if (isProd && t >= TAIL) {
            HU u; u.v = *(const h4v*)&A2[nxt][tm][tr0];
            ST64(&myRingH[((t & 15)*16 + tm)*128 + tr0], u.u);
            drain_vm();
            bar_lgkm();
            if (tid == 0) ST(myflag, t + 1);
        }

        // ================= FC head (l==4, t>=511; 3x) =================
        if (l == 4 && t >= 511) {
            const int iter = t - 511;
#pragma unroll
            for (int i = 0; i < 4; ++i)                  // zbsT[k][m] (f32, from regs)
                fcb[r*18 + quad*4 + i] = fmaxf(hv[i], 0.f);
            bar_lgkm();
            const int o = tid & 127, mq = tid >> 7;      // FC1: 512 thr, 4 m each
            float a0 = b1[o], a1 = a0, a2 = a0, a3 = a0;
#pragma unroll 8
            for (int k = 0; k < 128; ++k) {
                float w1v = W1[k*128 + o];
                const float* zr = &fcb[k*18 + mq*4];
                a0 = fmaf(zr[0], w1v, a0); a1 = fmaf(zr[1], w1v, a1);
                a2 = fmaf(zr[2], w1v, a2); a3 = fmaf(zr[3], w1v, a3);
            }
            bar_lgkm();                                  // all zbsT reads done
            fcb[(mq*4+0)*132 + o] = fmaxf(a0, 0.f);      // z2F[m][132]
            fcb[(mq*4+1)*132 + o] = fmaxf(a1, 0.f);
            fcb[(mq*4+2)*132 + o] = fmaxf(a2, 0.f);
            fcb[(mq*4+3)*132 + o] = fmaxf(a3, 0.f);
            bar_lgkm();
            if (tid < 256) {
                const int m = tid >> 4, oo = tid & 15;
                float acc2f = b2[oo];
#pragma unroll 8
                for (int k = 0; k < 128; ++k)
                    acc2f = fmaf(fcb[m*132 + k], W2[k*16 + oo], acc2f);
                if (iter == 2) {
                    out[(p*16 + m)*18 + 2 + oo] = acc2f;
                } else if (oo == 15) {
                    out[(p*16 + m)*18 + iter] = acc2f;
                    ST(&fcoutG[(p*2 + iter)*16 + m], acc2f);
                }
            }
            drain_vm();
            bar_lgkm();
            if (iter < 2 && tid == 0) ST(fcflagP, iter + 1);
        }
    }
}

extern "C" void kernel_launch(void* const* d_in, const int* in_sizes, int n_in,
                              void* d_out, int out_size, void* d_ws, size_t ws_size,
                              hipStream_t stream) {
    (void)in_sizes; (void)n_in; (void)out_size; (void)ws_size;  // needs ~4.1MB ws
    const float* x    = (const float*)d_in[0];
    // d_in[1] = future (18, hardcoded)
    const float* Wih0 = (const float*)d_in[2];
    const float* WihR = (const float*)d_in[3];
    const float* Whh  = (const float*)d_in[4];
    const float* bihp = (const float*)d_in[5];
    const float* bhhp = (const float*)d_in[6];
    const float* W1   = (const float*)d_in[7];
    const float* b1   = (const float*)d_in[8];
    const float* W2   = (const float*)d_in[9];
    const float* b2   = (const float*)d_in[10];
    char* ws = (char*)d_ws;

    lstm_init<<<256, 256, 0, stream>>>(WihR, Whh, bihp, bhhp, ws);
    lstm_main<<<10, 512, 0, stream>>>(x, Wih0, W1, b1, W2, b2, (float*)d_out, ws);
}

// Round 10
// 940.300 us; speedup vs baseline: 7.8742x; 7.8742x over previous
//
#include <hip/hip_runtime.h>

// LSTMPredictor: B=32,T=512,H=128,L=5,IN=1,OUT=16,future=18 -> one 514-step scan.
// R21 = R19 (best verified: 890us) + chunk-8 publish amortization, SLACK-PROOFED.
// R20 post-mortem (7404us): layer 4 publishes no flag after t=496 (no tail publish),
// but layer 3's t-16 backpressure needed flag>=497 at t=513 -> one GUARD timeout
// (65536 dependent agent-scope loads ~= 7.3ms) per dispatch. Fix arithmetic:
//   - RING 16 -> 32 (1MB ring, fits below WCATR_OFF).
//   - chunk publish (t&7)==0: halves spin-entry frequency (~300cyc exposed L2
//     round-trip per entry) and halves pub drain+barrier events.
//   - backpressure t-24: overwrite bound needs producer-ahead <= 32 (slot (t-1)&31
//     holds h(t-33)); t-24 allows <= 31 OK; consumer needs ahead >= 9 (chunk
//     staleness 7 + prefetch 2) -> ~15-step free-running elasticity band
//     (R20 had ~1-8 -> tight coupling).
//   - tail check: layer 3 max need = 513-24 = 489 <= layer 4 last chunk flag 496 OK
//     (R20: 497 > 496 FAIL -> GUARD).
// Closed case: SQ_LDS_BANK_CONFLICT = 4.0cyc per af ds_read_b128, layout-invariant
// (R14/R17/R19 triangulation) -> structural wave64 b128 cost, not fixable.
// Eliminated (measured): LDS read throughput (R13/R17), same-step L2 loads (R17
// +72%), pub drain + af latency (R18 neutral), per-step flag prefetch (R15, vmcnt
// FIFO), dependent MFMA gate chains (R14), rcp-paired activations (R16 +14us).
// Kept: R19 write-depermute rho(m)+stride 272; R13 both weight halves in 128 VGPRs;
// R12 scale-folded weights/bias, bias in MFMA C-init, v_exp/v_rcp activations.
// 10 WGs = 5 layers x 2 batch-halves, 512 thr, 1 WG/CU.

typedef _Float16 v8h __attribute__((ext_vector_type(8)));
typedef _Float16 h4v __attribute__((ext_vector_type(4)));
typedef float f4 __attribute__((ext_vector_type(4)));

#define RING 32
#define RMSK 31
#define TAIL 500
#define GUARD (1<<16)
#define ASTR 272                      // A2 row stride in f16 (136 dwords = 8 mod 32)

#define FLAGL_OFF   0                 // int flagL[2*5][64]
#define FCFLAG_OFF  (64*1024)        // int fcflag[2][64]
#define FCOUT_OFF   (128*1024)       // float fcout[2][2][16]
#define RING_OFF    (256*1024)       // f16 ring[8][32][16][128] = 1MB
#define WCATR_OFF   (2*1024*1024)    // f16 WcatR[5][512][128] (hh, scale-folded) = 640KB
#define WL_OFF      (3*1024*1024)    // f16 WLg[5][16][512][8] (ih, ktq-major, scale-folded)
#define BIASC_OFF   (4*1024*1024)    // f32 biasC[5][128][4] (scale-folded)

#define SCL_SIG (-1.4426950408889634f)   // -log2(e)
#define SCL_TNH (-2.8853900817779268f)   // -2*log2(e)

#define AGENT __HIP_MEMORY_SCOPE_AGENT
#define LD(p)    __hip_atomic_load((p),  __ATOMIC_RELAXED, AGENT)
#define ST(p,v)  __hip_atomic_store((p), (v), __ATOMIC_RELAXED, AGENT)
#define LD64(p)  __hip_atomic_load((const unsigned long long*)(p), __ATOMIC_RELAXED, AGENT)
#define ST64(p,v) __hip_atomic_store((unsigned long long*)(p), (v), __ATOMIC_RELAXED, AGENT)

union HU { unsigned long long u; h4v v; };

__device__ __forceinline__ void bar_lgkm() {
    asm volatile("s_waitcnt lgkmcnt(0)\n\ts_barrier" ::: "memory");
}
__device__ __forceinline__ void drain_vm() {
    asm volatile("s_waitcnt vmcnt(0)" ::: "memory");
}
__device__ __forceinline__ float exp2_hw(float x) {      // 2^x, one v_exp_f32
    float r; asm("v_exp_f32 %0, %1" : "=v"(r) : "v"(x)); return r;
}
__device__ __forceinline__ float sigm2(float s) {        // s = -log2e * x  -> sigmoid(x)
    return __builtin_amdgcn_rcpf(1.f + exp2_hw(s));
}
__device__ __forceinline__ float tanh2(float s) {        // s = -2log2e * x -> tanh(x)
    return fmaf(2.f, __builtin_amdgcn_rcpf(1.f + exp2_hw(s)), -1.f);
}

// -------- init: flags=0, WcatR (hh f16), WLg (ih f16 ktq-major), biasC — scale-folded ----
__global__ void lstm_init(const float* __restrict__ WihR, const float* __restrict__ Whh,
                          const float* __restrict__ bih,  const float* __restrict__ bhh,
                          char* __restrict__ ws)
{
    int idx = blockIdx.x * blockDim.x + threadIdx.x;
    int stride = gridDim.x * blockDim.x;
    int* wsi = (int*)ws;
    for (int i = idx; i < 65536; i += stride) wsi[i] = 0;

    _Float16* WR = (_Float16*)(ws + WCATR_OFF);        // [l][n][k<128]
    for (int i = idx; i < 5*512*128; i += stride) {
        int k = i & 127, n = (i >> 7) & 511, l = i >> 16;
        float s = ((n >> 7) == 2) ? SCL_TNH : SCL_SIG;
        WR[i] = (_Float16)(s * Whh[(l*512 + n)*128 + k]);
    }
    _Float16* WLp = (_Float16*)(ws + WL_OFF);          // [l][ktq][n][8]
    for (int i = idx; i < 5*16*512*8; i += stride) {
        int j = i & 7, n = (i >> 3) & 511, ktq = (i >> 12) & 15, l = i >> 16;
        int k = (ktq >> 2)*32 + (ktq & 3)*8 + j;       // ih column (0..127)
        float s = ((n >> 7) == 2) ? SCL_TNH : SCL_SIG;
        WLp[i] = (_Float16)(l > 0 ? s * WihR[((l-1)*512 + n)*128 + k] : 0.f);
    }
    float* BC = (float*)(ws + BIASC_OFF);              // [l][r][g]
    for (int i = idx; i < 5*128*4; i += stride) {
        int g = i & 3, r = (i >> 2) & 127, l = i >> 9;
        float s = (g == 2) ? SCL_TNH : SCL_SIG;
        BC[i] = s * (bih[l*512 + g*128 + r] + bhh[l*512 + g*128 + r]);
    }
}

// -------- main: persistent pipeline --------
__global__ void __launch_bounds__(512)
lstm_main(const float* __restrict__ x_in, const float* __restrict__ Wih0,
          const float* __restrict__ W1,   const float* __restrict__ b1,
          const float* __restrict__ W2,   const float* __restrict__ b2,
          float* __restrict__ out, char* __restrict__ ws)
{
    __shared__ __align__(16) _Float16 A2[2][16][ASTR];  // 17KB: A dbuf, PHYSICAL rows
    __shared__ float  fcb[2304];                        // 9.2KB: FC scratch (zbsT / z2F)
    __shared__ float  xcur[2][16];                      // l0: x[t] dbuf

    const int tid  = threadIdx.x;
    const int lane = tid & 63;
    const int w    = tid >> 6;              // wave 0..7 -> n-tiles {w,8+w,16+w,24+w}
    const int col  = lane & 15, quad = lane >> 4;
    const int r    = w*16 + col;            // this lane's hidden row
    const int rowR = ((col & 3) << 2) | (col >> 2);  // rho(col): physical row for A-reads
    const int p = blockIdx.x / 5, l = blockIdx.x % 5;
    const bool isProd = (l < 4), isCons = (l > 0);
    const int tm = tid >> 5, tr0 = (tid & 31) * 4;   // transport map: (phys row, r0)

    int*   flagL  = (int*)(ws + FLAGL_OFF);
    int*   fcflagP= (int*)(ws + FCFLAG_OFF) + p*64;
    float* fcoutG = (float*)(ws + FCOUT_OFF);
    _Float16* ringH = (_Float16*)(ws + RING_OFF);
    const _Float16* WR  = (const _Float16*)(ws + WCATR_OFF) + l*512*128;
    const _Float16* WLh = (const _Float16*)(ws + WL_OFF) + (size_t)l*65536;

    int* upflag = flagL + (p*5 + (l > 0 ? l-1 : 0))*64;
    int* dnflag = flagL + (p*5 + (l < 4 ? l+1 : 4))*64;
    int* myflag = flagL + (p*5 + l)*64;
    _Float16* upRingH = ringH + (p*4 + (l > 0 ? l-1 : 0))*RING*2048;
    _Float16* myRingH = ringH + (p*4 + (l < 4 ? l   : 0))*RING*2048;

    // ---- hh weights: registers (64 VGPRs) ----
    v8h bf[4][4];
#pragma unroll
    for (int q = 0; q < 4; ++q)
#pragma unroll
        for (int kt = 0; kt < 4; ++kt)
            bf[q][kt] = *(const v8h*)&WR[((q*8 + w)*16 + col)*128 + kt*32 + quad*8];

    // ---- ih weights: registers (64 VGPRs), one-time load ----
    v8h wfr[4][4];                       // [kt-4][q]
    if (isCons) {
#pragma unroll
        for (int kq = 0; kq < 4; ++kq)
#pragma unroll
            for (int q = 0; q < 4; ++q)
                wfr[kq][q] = *(const v8h*)&WLh[(((kq*4 + quad)*512) + (q*8 + w)*16 + col)*8];
    } else {
#pragma unroll
        for (int kq = 0; kq < 4; ++kq)
#pragma unroll
            for (int q = 0; q < 4; ++q)
                wfr[kq][q] = (v8h)(_Float16)0.f;
    }

    // ---- loop-invariant per-lane constants: bias (scale-folded) + l0 input weights ----
    const f4 bvR = ((const f4*)(ws + BIASC_OFF))[l*128 + r];
    f4 wxR = (f4){0.f, 0.f, 0.f, 0.f};
    if (l == 0) {
        wxR.x = SCL_SIG * Wih0[r];
        wxR.y = SCL_SIG * Wih0[128 + r];
        wxR.z = SCL_TNH * Wih0[256 + r];
        wxR.w = SCL_SIG * Wih0[384 + r];
    }

    for (int i = tid; i < 2*16*ASTR; i += 512) ((_Float16*)A2)[i] = (_Float16)0.f;
    if (l == 0 && tid < 16) xcur[0][tid] = x_in[(p*16 + tid)*512];

    int lastup = 0, lastdn = 0, lastfc = 0;
    if (isCons) {                       // seed up-h(0) (first chunk publish at t=8)
        int g = 0;
        while (lastup < 1) { if (++g > GUARD) break; lastup = LD(upflag); }
        HU u; u.u = LD64(&upRingH[(0*16 + tm)*128 + tr0]);
        *(h4v*)&A2[0][tm][128 + tr0] = u.v;
    }
    __syncthreads();

    float c[4] = {0.f, 0.f, 0.f, 0.f};

    for (int t = 0; t < 514; ++t) {
        const int cur = t & 1, nxt = (t + 1) & 1;

        // ---- steady ring store of h(t-1) + chunk-8 publish (physical rows) ----
        if (isProd && t > 0 && t <= TAIL) {
            HU u; u.v = *(const h4v*)&A2[cur][tm][tr0];
            ST64(&myRingH[(((t-1) & RMSK)*16 + tm)*128 + tr0], u.u);
        }
        if (t > 0 && t <= TAIL && (t & 7) == 0) {
            drain_vm();
            bar_lgkm();
            if (tid == 0) ST(myflag, t);
        }

        // ---- steady prefetch up-h(t+1) ----
        unsigned long long rv = 0;
        if (isCons && t + 1 < TAIL) {
            if (lastup < t + 2) {
                int g = 0;
                while (lastup < t + 2) { if (++g > GUARD) break; lastup = LD(upflag); }
            }
            rv = LD64(&upRingH[(((t+1) & RMSK)*16 + tm)*128 + tr0]);
        }
        // ---- tail current-fetch up-h(t) ----
        if (isCons && t >= TAIL) {
            if (lastup < t + 1) {
                int g = 0;
                while (lastup < t + 1) { if (++g > GUARD) break; lastup = LD(upflag); }
            }
            HU u; u.u = LD64(&upRingH[((t & RMSK)*16 + tm)*128 + tr0]);
            *(h4v*)&A2[cur][tm][128 + tr0] = u.v;
        }
        if (isCons && t >= TAIL) bar_lgkm();

        // ---- l0 x prefetch (steady) ----
        if (l == 0 && t + 1 < 512 && tid < 16)
            xcur[nxt][tid] = x_in[(p*16 + tid)*512 + (t+1)];
        // ---- backpressure (rare); slot (t-1)&31 holds h(t-33): overwrite needs
        //      flag >= t-32; t-24 leaves 8-step margin. Tail bound: layer 3 max
        //      need 513-24=489 <= layer 4's last chunk flag 496. ----
        if (isProd && t >= RING && lastdn < t - 24) {
            int g = 0;
            while (lastdn < t - 24) { if (++g > GUARD) break; lastdn = LD(dnflag); }
        }

        // ================= MFMA: gates = A @ [Whh | Wih]^T (bias in C-init) ==========
        // kt-outer / q-inner: 4 independent accumulators, dep-distance 4 -> pipelined.
        // A-read at physical row rho(col): uniform 8 dwords/bank.
        const _Float16* Ac = &A2[cur][0][0] + rowR*ASTR + quad*8;
        f4 acc[4];
        acc[0] = (f4){bvR.x, bvR.x, bvR.x, bvR.x};
        acc[1] = (f4){bvR.y, bvR.y, bvR.y, bvR.y};
        acc[2] = (f4){bvR.z, bvR.z, bvR.z, bvR.z};
        acc[3] = (f4){bvR.w, bvR.w, bvR.w, bvR.w};
#pragma unroll
        for (int kt = 0; kt < 4; ++kt) {                 // hh: B from registers
            v8h af = *(const v8h*)(Ac + kt*32);
#pragma unroll
            for (int q = 0; q < 4; ++q)
                acc[q] = __builtin_amdgcn_mfma_f32_16x16x32_f16(af, bf[q][kt], acc[q], 0, 0, 0);
        }
        if (isCons) {
#pragma unroll
            for (int kt = 4; kt < 8; ++kt) {             // ih: B from registers
                v8h af = *(const v8h*)(Ac + 128 + (kt-4)*32);
#pragma unroll
                for (int q = 0; q < 4; ++q)
                    acc[q] = __builtin_amdgcn_mfma_f32_16x16x32_f16(af, wfr[kt-4][q], acc[q], 0, 0, 0);
            }
        }

        // ---- l0 tail: feedback x into xcur[cur] ----
        if (l == 0 && t >= 512) {
            if (tid < 16) {
                int need = t - 511, g = 0;
                while (lastfc < need) { if (++g > GUARD) break; lastfc = LD(fcflagP); }
                xcur[cur][tid] = LD(&fcoutG[(p*2 + (t - 512))*16 + tid]);
            }
            bar_lgkm();
        }

        // ================= cell update: IN-REGISTER (lane owns 4 cells) ==========
        float xts[4];
        if (l == 0) {
#pragma unroll
            for (int i = 0; i < 4; ++i) xts[i] = xcur[cur][quad*4 + i];
        }
        float hv[4];
#pragma unroll
        for (int i = 0; i < 4; ++i) {
            float gi = acc[0][i], gf = acc[1][i];
            float gG = acc[2][i], gO = acc[3][i];
            if (l == 0) {
                gi = fmaf(wxR.x, xts[i], gi); gf = fmaf(wxR.y, xts[i], gf);
                gG = fmaf(wxR.z, xts[i], gG); gO = fmaf(wxR.w, xts[i], gO);
            }
            float si = sigm2(gi), sf = sigm2(gf), gt = tanh2(gG), so = sigm2(gO);
            c[i] = fmaf(sf, c[i], si * gt);
            hv[i] = so * tanh2(c[i] * SCL_TNH);
            // physical row rho(m) = i*4+quad: bank octets {0,8,16,24} disjoint.
            A2[nxt][i*4 + quad][r] = (_Float16)hv[i];    // own-h(t) for step t+1
        }
        if (isCons && t + 1 < TAIL) {                    // prefetched up-h(t+1)
            HU u; u.u = rv;
            *(h4v*)&A2[nxt][tm][128 + tr0] = u.v;
        }
        bar_lgkm();

        // ---- tail: store h(t) + per-step publish ----
        if (isProd && t >= TAIL) {
            HU u; u.v = *(const h4v*)&A2[nxt][tm][tr0];
            ST64(&myRingH[((t & RMSK)*16 + tm)*128 + tr0], u.u);
            drain_vm();
            bar_lgkm();
            if (tid == 0) ST(myflag, t + 1);
        }

        // ================= FC head (l==4, t>=511; 3x) =================
        if (l == 4 && t >= 511) {
            const int iter = t - 511;
#pragma unroll
            for (int i = 0; i < 4; ++i)                  // zbsT[k][m] (f32, from regs)
                fcb[r*18 + quad*4 + i] = fmaxf(hv[i], 0.f);
            bar_lgkm();
            const int o = tid & 127, mq = tid >> 7;      // FC1: 512 thr, 4 m each
            float a0 = b1[o], a1 = a0, a2 = a0, a3 = a0;
#pragma unroll 8
            for (int k = 0; k < 128; ++k) {
                float w1v = W1[k*128 + o];
                const float* zr = &fcb[k*18 + mq*4];
                a0 = fmaf(zr[0], w1v, a0); a1 = fmaf(zr[1], w1v, a1);
                a2 = fmaf(zr[2], w1v, a2); a3 = fmaf(zr[3], w1v, a3);
            }
            bar_lgkm();                                  // all zbsT reads done
            fcb[(mq*4+0)*132 + o] = fmaxf(a0, 0.f);      // z2F[m][132]
            fcb[(mq*4+1)*132 + o] = fmaxf(a1, 0.f);
            fcb[(mq*4+2)*132 + o] = fmaxf(a2, 0.f);
            fcb[(mq*4+3)*132 + o] = fmaxf(a3, 0.f);
            bar_lgkm();
            if (tid < 256) {
                const int m = tid >> 4, oo = tid & 15;
                float acc2f = b2[oo];
#pragma unroll 8
                for (int k = 0; k < 128; ++k)
                    acc2f = fmaf(fcb[m*132 + k], W2[k*16 + oo], acc2f);
                if (iter == 2) {
                    out[(p*16 + m)*18 + 2 + oo] = acc2f;
                } else if (oo == 15) {
                    out[(p*16 + m)*18 + iter] = acc2f;
                    ST(&fcoutG[(p*2 + iter)*16 + m], acc2f);
                }
            }
            drain_vm();
            bar_lgkm();
            if (iter < 2 && tid == 0) ST(fcflagP, iter + 1);
        }
    }
}

extern "C" void kernel_launch(void* const* d_in, const int* in_sizes, int n_in,
                              void* d_out, int out_size, void* d_ws, size_t ws_size,
                              hipStream_t stream) {
    (void)in_sizes; (void)n_in; (void)out_size; (void)ws_size;  // needs ~4.1MB ws
    const float* x    = (const float*)d_in[0];
    // d_in[1] = future (18, hardcoded)
    const float* Wih0 = (const float*)d_in[2];
    const float* WihR = (const float*)d_in[3];
    const float* Whh  = (const float*)d_in[4];
    const float* bihp = (const float*)d_in[5];
    const float* bhhp = (const float*)d_in[6];
    const float* W1   = (const float*)d_in[7];
    const float* b1   = (const float*)d_in[8];
    const float* W2   = (const float*)d_in[9];
    const float* b2   = (const float*)d_in[10];
    char* ws = (char*)d_ws;

    lstm_init<<<256, 256, 0, stream>>>(WihR, Whh, bihp, bhhp, ws);
    lstm_main<<<10, 512, 0, stream>>>(x, Wih0, W1, b1, W2, b2, (float*)d_out, ws);
}